// Round 4
// baseline (844.157 us; speedup 1.0000x reference)
//
#include <hip/hip_runtime.h>
#include <hip/hip_bf16.h>

// Problem constants (from reference): B=64, S=2048, D_ENC=D_DEC=UNITS=512
#define BATCH 64
#define SEQ   2048
#define DIM   512
#define MROWS (BATCH * SEQ)   // 131072 rows of the big GEMM

typedef short bf16x8 __attribute__((ext_vector_type(8)));
typedef float f32x4  __attribute__((ext_vector_type(4)));

static __device__ __forceinline__ unsigned short f2bf(float f) {
    // round-to-nearest-even fp32 -> bf16
    union { float f; unsigned u; } v; v.f = f;
    unsigned u = v.u;
    u += 0x7FFFu + ((u >> 16) & 1u);
    return (unsigned short)(u >> 16);
}

// fast tanh: tanh(x) = (e^{2x}-1)/(e^{2x}+1), e^{2x} = 2^{x*2log2(e)}
static __device__ __forceinline__ float tanh_fast(float x) {
    float xc = fminf(20.0f, fmaxf(-20.0f, x));
#if __has_builtin(__builtin_amdgcn_exp2f)
    float t = __builtin_amdgcn_exp2f(2.885390082f * xc);
#else
    float t = exp2f(2.885390082f * xc);
#endif
#if __has_builtin(__builtin_amdgcn_rcpf)
    return (t - 1.0f) * __builtin_amdgcn_rcpf(t + 1.0f);
#else
    return (t - 1.0f) / (t + 1.0f);
#endif
}

// global -> LDS async DMA, 16B per lane. LDS dest must be wave-uniform base
// + lane*16 (m104/m108 caveat) — our chunk ids are lane-consecutive.
typedef __attribute__((address_space(1))) const unsigned int gu32;
typedef __attribute__((address_space(3))) unsigned int lu32;
static __device__ __forceinline__ void gload_lds16(const unsigned short* g,
                                                   unsigned short* l) {
    __builtin_amdgcn_global_load_lds((gu32*)g, (lu32*)l, 16, 0, 0);
}

// ---------------------------------------------------------------------------
// Kernel 0: W1 [k][u] fp32  ->  W1t [u][k] bf16   (512x512, tiny)
// ---------------------------------------------------------------------------
__global__ void prep_w1t_kernel(const float* __restrict__ W1,
                                unsigned short* __restrict__ w1t) {
    int stride = gridDim.x * blockDim.x;
    for (int i = blockIdx.x * blockDim.x + threadIdx.x; i < DIM * DIM; i += stride) {
        int k = i >> 9;
        int u = i & 511;
        w1t[u * DIM + k] = f2bf(W1[i]);
    }
}

// ---------------------------------------------------------------------------
// Kernel 1 (v2): pd[b][u] = dec[b,:] @ W2[:,u] + b1[u] + b2[u]
// grid (8 u-groups, 64 b), 256 threads = 64 u x 4 k-quarters.
// ---------------------------------------------------------------------------
__global__ void proj_dec_v2(const float* __restrict__ dec,
                            const float* __restrict__ W2,
                            const float* __restrict__ b1,
                            const float* __restrict__ b2,
                            float* __restrict__ pd) {
    __shared__ float sdec[DIM];
    __shared__ float red[4 * 64];
    const int ug = blockIdx.x;      // 0..7  -> u0 = ug*64
    const int b  = blockIdx.y;      // 0..63
    const int t  = threadIdx.x;     // 256
    sdec[t]       = dec[b * DIM + t];
    sdec[t + 256] = dec[b * DIM + t + 256];
    __syncthreads();
    const int u  = ug * 64 + (t & 63);
    const int kq = t >> 6;          // 0..3
    float acc = 0.f;
    #pragma unroll 4
    for (int k = kq * 128; k < kq * 128 + 128; ++k)
        acc += sdec[k] * W2[k * DIM + u];
    red[kq * 64 + (t & 63)] = acc;
    __syncthreads();
    if (t < 64) {
        int u_g = ug * 64 + t;
        float s = red[t] + red[64 + t] + red[128 + t] + red[192 + t]
                + b1[u_g] + b2[u_g];
        pd[b * DIM + u_g] = s;
    }
}

// ---------------------------------------------------------------------------
// Kernel 2 (v7): BM 64 -> 128 to halve the B-panel L2 re-fetch (R3 counters:
// stage-throughput-bound, 1.07 GB L2 traffic for B, MfmaUtil 16.6%, nothing
// saturated). 512 threads / 8 waves = 2 M-halves x 4 col-strips; per-wave
// tile stays 64x128 (same acc[8][4], same ~120 VGPR, same swizzled inner
// loop). LDS 80 KB -> 2 blocks/CU, 16 waves/CU. Keeps the proven v4/v6
// 2-barrier single-buffer round structure and the fused unnormalized-softmax
// context epilogue (scores -> e^s -> ctx partials from L2-hot enc tile).
// ---------------------------------------------------------------------------
#define BM7 128
#define BK7 64

__global__ __launch_bounds__(512, 4) void gemm_score_v7(
    const float* __restrict__ enc,            // [m][k] fp32
    const unsigned short* __restrict__ w1t,   // [u][k] bf16
    const float* __restrict__ pd,             // [b][u]
    const float* __restrict__ V,              // [u]
    float* __restrict__ scores,               // [M]
    float* __restrict__ cnum,                 // [B][DIM] atomic accumulators
    float* __restrict__ zacc)                 // [B]
{
    __shared__ unsigned short sA[BM7 * BK7];   // 16 KB
    __shared__ unsigned short sB[DIM * BK7];   // 64 KB

    const int tid  = threadIdx.x;     // 512
    const int lane = tid & 63;
    const int wave = tid >> 6;        // 0..7
    const int wm   = wave & 1;        // M half: rows wm*64..+63
    const int wn   = wave >> 1;       // col strip: u = wn*128..+127
    const int quad = lane >> 4;
    const int l15  = lane & 15;

    const int row0 = blockIdx.x * BM7;   // gridDim.x = 1024

    f32x4 acc[8][4];   // [j: col subtile 16][tr: row subtile 16]
    for (int j = 0; j < 8; ++j)
        for (int tr = 0; tr < 4; ++tr)
            acc[j][tr] = (f32x4){0.f, 0.f, 0.f, 0.f};

    for (int k0 = 0; k0 < DIM; k0 += BK7) {
        // stage B first (async DMA): 512 u's x 64 k = 4096 chunks, 8/thread
        for (int i = 0; i < 8; ++i) {
            int c  = i * 512 + tid;
            int r  = c >> 3;          // u = 0..511
            int cc = c & 7;
            int gc = cc ^ (r & 7);
            gload_lds16(w1t + (size_t)r * DIM + k0 + gc * 8, &sB[c * 8]);
        }
        // stage A: 128 rows x 64 k fp32 -> bf16 in-register, 1024 chunks,
        // 2/thread; XOR swizzle applied on the LDS write address.
        for (int i = 0; i < 2; ++i) {
            int c  = i * 512 + tid;
            int r  = c >> 3;          // 0..127
            int cc = c & 7;
            const float4* p =
                (const float4*)(enc + (size_t)(row0 + r) * DIM + k0 + cc * 8);
            float4 va = p[0], vb = p[1];
            union { ushort4 s[2]; uint4 q; } o;
            o.s[0].x = f2bf(va.x); o.s[0].y = f2bf(va.y);
            o.s[0].z = f2bf(va.z); o.s[0].w = f2bf(va.w);
            o.s[1].x = f2bf(vb.x); o.s[1].y = f2bf(vb.y);
            o.s[1].z = f2bf(vb.z); o.s[1].w = f2bf(vb.w);
            *(uint4*)(&sA[r * BK7 + ((cc ^ (r & 7)) * 8)]) = o.q;
        }
        __syncthreads();

        for (int kk = 0; kk < BK7; kk += 32) {
            int jc = (kk >> 3) + quad;   // global k-chunk 0..7
            bf16x8 af[4];
            for (int tr = 0; tr < 4; ++tr) {
                int am = wm * 64 + tr * 16 + l15;
                af[tr] = *(const bf16x8*)(&sA[am * BK7 + ((jc ^ (am & 7)) * 8)]);
            }
            for (int j = 0; j < 8; ++j) {
                int u = wn * 128 + j * 16 + l15;
                bf16x8 bfr = *(const bf16x8*)(&sB[u * BK7 + ((jc ^ (u & 7)) * 8)]);
                for (int tr = 0; tr < 4; ++tr)
                    acc[j][tr] = __builtin_amdgcn_mfma_f32_16x16x32_bf16(
                        af[tr], bfr, acc[j][tr], 0, 0, 0);
            }
        }
        __syncthreads();
    }

    // ---- epilogue part 1: tanh + V-dot over this wave's 128 u's ----
    const int b = row0 >> 11;   // 128-row blocks never cross a batch
    float sacc[4][4];
    for (int tr = 0; tr < 4; ++tr)
        for (int r = 0; r < 4; ++r) sacc[tr][r] = 0.f;

    for (int j = 0; j < 8; ++j) {
        int u_g   = wn * 128 + j * 16 + l15;
        float pdv = pd[b * DIM + u_g];
        float vv  = V[u_g];
        for (int tr = 0; tr < 4; ++tr)
            for (int r = 0; r < 4; ++r)
                sacc[tr][r] += tanh_fast(acc[j][tr][r] + pdv) * vv;
    }
    // reduce across the 16 col-lanes (lane bits 0..3)
    for (int tr = 0; tr < 4; ++tr)
        for (int r = 0; r < 4; ++r) {
            float v = sacc[tr][r];
            v += __shfl_xor(v, 1);
            v += __shfl_xor(v, 2);
            v += __shfl_xor(v, 4);
            v += __shfl_xor(v, 8);
            sacc[tr][r] = v;
        }
    // cross-wave reduce via LDS (reuse sA; fenced by the loop's last barrier)
    float* red  = (float*)sA;           // 8 waves x 64 local rows = 2 KB
    float* eLds = ((float*)sA) + 512;   // 128 floats of e^score
    if (l15 == 0) {
        for (int tr = 0; tr < 4; ++tr)
            for (int r = 0; r < 4; ++r)
                red[wave * 64 + tr * 16 + quad * 4 + r] = sacc[tr][r];
    }
    __syncthreads();
    if (tid < BM7) {
        int m  = tid >> 6;      // which M half
        int lr = tid & 63;      // local row
        // waves with wm==m are wave = wn*2+m, wn = 0..3
        float s = red[(0 * 2 + m) * 64 + lr] + red[(1 * 2 + m) * 64 + lr]
                + red[(2 * 2 + m) * 64 + lr] + red[(3 * 2 + m) * 64 + lr];
        scores[row0 + tid] = s;
        eLds[tid] = expf(s);    // unnormalized softmax numerator
    }
    __syncthreads();

    // ---- epilogue part 2: context partials (no second enc pass later) ----
    // zacc partials: waves 0,1 reduce 64 e-values each
    if (wave < 2) {
        float e = eLds[wave * 64 + lane];
        e += __shfl_xor(e, 32);
        e += __shfl_xor(e, 16);
        e += __shfl_xor(e, 8);
        e += __shfl_xor(e, 4);
        e += __shfl_xor(e, 2);
        e += __shfl_xor(e, 1);
        if (lane == 0) atomicAdd(&zacc[b], e);
    }
    // cnum partial: thread owns dim tid; rows re-read from L2-hot enc
    // (per-row the 512 threads read a contiguous 2 KB line).
    {
        const float* ebase = enc + (size_t)row0 * DIM + tid;
        float cx = 0.f;
        #pragma unroll 4
        for (int r = 0; r < BM7; ++r)
            cx += eLds[r] * ebase[(size_t)r * DIM];
        atomicAdd(&cnum[b * DIM + tid], cx);
    }
}

// ---------------------------------------------------------------------------
// Kernel 3: finalize — normalize attn and ctx. grid (4 seq-chunks, 64 b).
// expf(scores) here is bit-identical to the epilogue's (same stored input,
// same function), so attn sums to 1 within fp error.
// ---------------------------------------------------------------------------
__global__ void finalize_kernel(const float* __restrict__ scores,
                                const float* __restrict__ cnum,
                                const float* __restrict__ zacc,
                                float* __restrict__ attn,
                                float* __restrict__ ctx) {
    const int c = blockIdx.x;   // 0..3
    const int b = blockIdx.y;   // 0..63
    const int t = threadIdx.x;  // 256
    const float invZ = 1.0f / zacc[b];
    for (int i = 0; i < 2; ++i) {
        int s = c * 512 + t + i * 256;
        attn[(size_t)b * SEQ + s] = expf(scores[(size_t)b * SEQ + s]) * invZ;
    }
    if (c == 0) {
        ctx[b * DIM + t]       = cnum[b * DIM + t]       * invZ;
        ctx[b * DIM + t + 256] = cnum[b * DIM + t + 256] * invZ;
    }
}

// ---------------------------------------------------------------------------
// Launch: memset(131.3 KB) + 4 kernels. Workspace need: ~1.3 MB.
// ---------------------------------------------------------------------------
extern "C" void kernel_launch(void* const* d_in, const int* in_sizes, int n_in,
                              void* d_out, int out_size, void* d_ws, size_t ws_size,
                              hipStream_t stream) {
    const float* enc = (const float*)d_in[0];   // [64,2048,512]
    const float* dec = (const float*)d_in[1];   // [64,512]
    const float* W1  = (const float*)d_in[2];   // [512,512]
    const float* b1  = (const float*)d_in[3];   // [512]
    const float* W2  = (const float*)d_in[4];   // [512,512]
    const float* b2  = (const float*)d_in[5];   // [512]
    const float* V   = (const float*)d_in[6];   // [512,1]
    // d_in[7] = bv: dead (softmax shift-invariance)

    float* out  = (float*)d_out;
    float* ctx  = out;                 // [64,512]
    float* attn = out + BATCH * DIM;   // [64,2048]

    char* ws = (char*)d_ws;
    float* pd            = (float*)ws;                                  // 128 KB
    unsigned short* w1t  = (unsigned short*)(ws + 131072);              // 512 KB
    float* scores        = (float*)(ws + 131072 + 524288);              // 512 KB
    float* cnum          = (float*)(ws + 131072 + 524288 + 524288);     // 128 KB
    float* zacc          = (float*)(ws + 131072 + 524288 + 524288 + 131072); // 256 B

    // zero the atomic accumulators (cnum + zacc are contiguous)
    hipMemsetAsync(cnum, 0, (size_t)BATCH * DIM * 4 + BATCH * 4, stream);

    prep_w1t_kernel<<<256, 256, 0, stream>>>(W1, w1t);
    proj_dec_v2<<<dim3(8, BATCH), 256, 0, stream>>>(dec, W2, b1, b2, pd);
    gemm_score_v7<<<MROWS / BM7, 512, 0, stream>>>(enc, w1t, pd, V, scores,
                                                   cnum, zacc);
    finalize_kernel<<<dim3(4, BATCH), 256, 0, stream>>>(scores, cnum, zacc,
                                                        attn, ctx);
}

// Round 5
// 479.718 us; speedup vs baseline: 1.7597x; 1.7597x over previous
//
#include <hip/hip_runtime.h>
#include <hip/hip_bf16.h>

// Problem constants (from reference): B=64, S=2048, D_ENC=D_DEC=UNITS=512
#define BATCH 64
#define SEQ   2048
#define DIM   512
#define MROWS (BATCH * SEQ)   // 131072 rows of the big GEMM

typedef short bf16x8 __attribute__((ext_vector_type(8)));
typedef float f32x4  __attribute__((ext_vector_type(4)));

static __device__ __forceinline__ unsigned short f2bf(float f) {
    // round-to-nearest-even fp32 -> bf16
    union { float f; unsigned u; } v; v.f = f;
    unsigned u = v.u;
    u += 0x7FFFu + ((u >> 16) & 1u);
    return (unsigned short)(u >> 16);
}

// fast tanh: tanh(x) = (e^{2x}-1)/(e^{2x}+1), e^{2x} = 2^{x*2log2(e)}
static __device__ __forceinline__ float tanh_fast(float x) {
    float xc = fminf(20.0f, fmaxf(-20.0f, x));
#if __has_builtin(__builtin_amdgcn_exp2f)
    float t = __builtin_amdgcn_exp2f(2.885390082f * xc);
#else
    float t = exp2f(2.885390082f * xc);
#endif
#if __has_builtin(__builtin_amdgcn_rcpf)
    return (t - 1.0f) * __builtin_amdgcn_rcpf(t + 1.0f);
#else
    return (t - 1.0f) / (t + 1.0f);
#endif
}

// global -> LDS async DMA, 16B per lane. LDS dest must be wave-uniform base
// + lane*16 (m104/m108 caveat) — our chunk ids are lane-consecutive.
typedef __attribute__((address_space(1))) const unsigned int gu32;
typedef __attribute__((address_space(3))) unsigned int lu32;
static __device__ __forceinline__ void gload_lds16(const unsigned short* g,
                                                   unsigned short* l) {
    __builtin_amdgcn_global_load_lds((gu32*)g, (lu32*)l, 16, 0, 0);
}

// ---------------------------------------------------------------------------
// Kernel 0: W1 [k][u] fp32  ->  W1t [u][k] bf16   (512x512, tiny)
// ---------------------------------------------------------------------------
__global__ void prep_w1t_kernel(const float* __restrict__ W1,
                                unsigned short* __restrict__ w1t) {
    int stride = gridDim.x * blockDim.x;
    for (int i = blockIdx.x * blockDim.x + threadIdx.x; i < DIM * DIM; i += stride) {
        int k = i >> 9;
        int u = i & 511;
        w1t[u * DIM + k] = f2bf(W1[i]);
    }
}

// ---------------------------------------------------------------------------
// Kernel 1 (v2): pd[b][u] = dec[b,:] @ W2[:,u] + b1[u] + b2[u]
// grid (8 u-groups, 64 b), 256 threads = 64 u x 4 k-quarters.
// ---------------------------------------------------------------------------
__global__ void proj_dec_v2(const float* __restrict__ dec,
                            const float* __restrict__ W2,
                            const float* __restrict__ b1,
                            const float* __restrict__ b2,
                            float* __restrict__ pd) {
    __shared__ float sdec[DIM];
    __shared__ float red[4 * 64];
    const int ug = blockIdx.x;      // 0..7  -> u0 = ug*64
    const int b  = blockIdx.y;      // 0..63
    const int t  = threadIdx.x;     // 256
    sdec[t]       = dec[b * DIM + t];
    sdec[t + 256] = dec[b * DIM + t + 256];
    __syncthreads();
    const int u  = ug * 64 + (t & 63);
    const int kq = t >> 6;          // 0..3
    float acc = 0.f;
    #pragma unroll 4
    for (int k = kq * 128; k < kq * 128 + 128; ++k)
        acc += sdec[k] * W2[k * DIM + u];
    red[kq * 64 + (t & 63)] = acc;
    __syncthreads();
    if (t < 64) {
        int u_g = ug * 64 + t;
        float s = red[t] + red[64 + t] + red[128 + t] + red[192 + t]
                + b1[u_g] + b2[u_g];
        pd[b * DIM + u_g] = s;
    }
}

// ---------------------------------------------------------------------------
// Kernel 2 (v7b): identical to v7 (BM=128, 8 waves, fused softmax-context
// epilogue) EXCEPT __launch_bounds__(512, 2). R4's (512, 4) declared 4
// waves/EU minimum -> 128-VGPR cap -> acc[8][4] spilled to scratch
// (VGPR_Count=64, WRITE_SIZE=1.2 GB, 570 us). (512, 2) gives a 256-VGPR
// budget; expected ~120-160 VGPR, zero spill; occupancy still 2 blocks/CU
// (LDS 80 KB) = 16 waves/CU.
// ---------------------------------------------------------------------------
#define BM7 128
#define BK7 64

__global__ __launch_bounds__(512, 2) void gemm_score_v7b(
    const float* __restrict__ enc,            // [m][k] fp32
    const unsigned short* __restrict__ w1t,   // [u][k] bf16
    const float* __restrict__ pd,             // [b][u]
    const float* __restrict__ V,              // [u]
    float* __restrict__ scores,               // [M]
    float* __restrict__ cnum,                 // [B][DIM] atomic accumulators
    float* __restrict__ zacc)                 // [B]
{
    __shared__ unsigned short sA[BM7 * BK7];   // 16 KB
    __shared__ unsigned short sB[DIM * BK7];   // 64 KB

    const int tid  = threadIdx.x;     // 512
    const int lane = tid & 63;
    const int wave = tid >> 6;        // 0..7
    const int wm   = wave & 1;        // M half: rows wm*64..+63
    const int wn   = wave >> 1;       // col strip: u = wn*128..+127
    const int quad = lane >> 4;
    const int l15  = lane & 15;

    const int row0 = blockIdx.x * BM7;   // gridDim.x = 1024

    f32x4 acc[8][4];   // [j: col subtile 16][tr: row subtile 16]
    for (int j = 0; j < 8; ++j)
        for (int tr = 0; tr < 4; ++tr)
            acc[j][tr] = (f32x4){0.f, 0.f, 0.f, 0.f};

    for (int k0 = 0; k0 < DIM; k0 += BK7) {
        // stage B first (async DMA): 512 u's x 64 k = 4096 chunks, 8/thread
        for (int i = 0; i < 8; ++i) {
            int c  = i * 512 + tid;
            int r  = c >> 3;          // u = 0..511
            int cc = c & 7;
            int gc = cc ^ (r & 7);
            gload_lds16(w1t + (size_t)r * DIM + k0 + gc * 8, &sB[c * 8]);
        }
        // stage A: 128 rows x 64 k fp32 -> bf16 in-register, 1024 chunks,
        // 2/thread; XOR swizzle applied on the LDS write address.
        for (int i = 0; i < 2; ++i) {
            int c  = i * 512 + tid;
            int r  = c >> 3;          // 0..127
            int cc = c & 7;
            const float4* p =
                (const float4*)(enc + (size_t)(row0 + r) * DIM + k0 + cc * 8);
            float4 va = p[0], vb = p[1];
            union { ushort4 s[2]; uint4 q; } o;
            o.s[0].x = f2bf(va.x); o.s[0].y = f2bf(va.y);
            o.s[0].z = f2bf(va.z); o.s[0].w = f2bf(va.w);
            o.s[1].x = f2bf(vb.x); o.s[1].y = f2bf(vb.y);
            o.s[1].z = f2bf(vb.z); o.s[1].w = f2bf(vb.w);
            *(uint4*)(&sA[r * BK7 + ((cc ^ (r & 7)) * 8)]) = o.q;
        }
        __syncthreads();

        for (int kk = 0; kk < BK7; kk += 32) {
            int jc = (kk >> 3) + quad;   // global k-chunk 0..7
            bf16x8 af[4];
            for (int tr = 0; tr < 4; ++tr) {
                int am = wm * 64 + tr * 16 + l15;
                af[tr] = *(const bf16x8*)(&sA[am * BK7 + ((jc ^ (am & 7)) * 8)]);
            }
            for (int j = 0; j < 8; ++j) {
                int u = wn * 128 + j * 16 + l15;
                bf16x8 bfr = *(const bf16x8*)(&sB[u * BK7 + ((jc ^ (u & 7)) * 8)]);
                for (int tr = 0; tr < 4; ++tr)
                    acc[j][tr] = __builtin_amdgcn_mfma_f32_16x16x32_bf16(
                        af[tr], bfr, acc[j][tr], 0, 0, 0);
            }
        }
        __syncthreads();
    }

    // ---- epilogue part 1: tanh + V-dot over this wave's 128 u's ----
    const int b = row0 >> 11;   // 128-row blocks never cross a batch
    float sacc[4][4];
    for (int tr = 0; tr < 4; ++tr)
        for (int r = 0; r < 4; ++r) sacc[tr][r] = 0.f;

    for (int j = 0; j < 8; ++j) {
        int u_g   = wn * 128 + j * 16 + l15;
        float pdv = pd[b * DIM + u_g];
        float vv  = V[u_g];
        for (int tr = 0; tr < 4; ++tr)
            for (int r = 0; r < 4; ++r)
                sacc[tr][r] += tanh_fast(acc[j][tr][r] + pdv) * vv;
    }
    // reduce across the 16 col-lanes (lane bits 0..3)
    for (int tr = 0; tr < 4; ++tr)
        for (int r = 0; r < 4; ++r) {
            float v = sacc[tr][r];
            v += __shfl_xor(v, 1);
            v += __shfl_xor(v, 2);
            v += __shfl_xor(v, 4);
            v += __shfl_xor(v, 8);
            sacc[tr][r] = v;
        }
    // cross-wave reduce via LDS (reuse sA; fenced by the loop's last barrier)
    float* red  = (float*)sA;           // 8 waves x 64 local rows = 2 KB
    float* eLds = ((float*)sA) + 512;   // 128 floats of e^score
    if (l15 == 0) {
        for (int tr = 0; tr < 4; ++tr)
            for (int r = 0; r < 4; ++r)
                red[wave * 64 + tr * 16 + quad * 4 + r] = sacc[tr][r];
    }
    __syncthreads();
    if (tid < BM7) {
        int m  = tid >> 6;      // which M half
        int lr = tid & 63;      // local row
        // waves with wm==m are wave = wn*2+m, wn = 0..3
        float s = red[(0 * 2 + m) * 64 + lr] + red[(1 * 2 + m) * 64 + lr]
                + red[(2 * 2 + m) * 64 + lr] + red[(3 * 2 + m) * 64 + lr];
        scores[row0 + tid] = s;
        eLds[tid] = expf(s);    // unnormalized softmax numerator
    }
    __syncthreads();

    // ---- epilogue part 2: context partials (no second enc pass later) ----
    // zacc partials: waves 0,1 reduce 64 e-values each
    if (wave < 2) {
        float e = eLds[wave * 64 + lane];
        e += __shfl_xor(e, 32);
        e += __shfl_xor(e, 16);
        e += __shfl_xor(e, 8);
        e += __shfl_xor(e, 4);
        e += __shfl_xor(e, 2);
        e += __shfl_xor(e, 1);
        if (lane == 0) atomicAdd(&zacc[b], e);
    }
    // cnum partial: thread owns dim tid; rows re-read from L2-hot enc
    // (per-row the 512 threads read a contiguous 2 KB line).
    {
        const float* ebase = enc + (size_t)row0 * DIM + tid;
        float cx = 0.f;
        #pragma unroll 4
        for (int r = 0; r < BM7; ++r)
            cx += eLds[r] * ebase[(size_t)r * DIM];
        atomicAdd(&cnum[b * DIM + tid], cx);
    }
}

// ---------------------------------------------------------------------------
// Kernel 3: finalize — normalize attn and ctx. grid (4 seq-chunks, 64 b).
// expf(scores) here is bit-identical to the epilogue's (same stored input,
// same function), so attn sums to 1 within fp error.
// ---------------------------------------------------------------------------
__global__ void finalize_kernel(const float* __restrict__ scores,
                                const float* __restrict__ cnum,
                                const float* __restrict__ zacc,
                                float* __restrict__ attn,
                                float* __restrict__ ctx) {
    const int c = blockIdx.x;   // 0..3
    const int b = blockIdx.y;   // 0..63
    const int t = threadIdx.x;  // 256
    const float invZ = 1.0f / zacc[b];
    for (int i = 0; i < 2; ++i) {
        int s = c * 512 + t + i * 256;
        attn[(size_t)b * SEQ + s] = expf(scores[(size_t)b * SEQ + s]) * invZ;
    }
    if (c == 0) {
        ctx[b * DIM + t]       = cnum[b * DIM + t]       * invZ;
        ctx[b * DIM + t + 256] = cnum[b * DIM + t + 256] * invZ;
    }
}

// ---------------------------------------------------------------------------
// Launch: memset(131.3 KB) + 4 kernels. Workspace need: ~1.3 MB.
// ---------------------------------------------------------------------------
extern "C" void kernel_launch(void* const* d_in, const int* in_sizes, int n_in,
                              void* d_out, int out_size, void* d_ws, size_t ws_size,
                              hipStream_t stream) {
    const float* enc = (const float*)d_in[0];   // [64,2048,512]
    const float* dec = (const float*)d_in[1];   // [64,512]
    const float* W1  = (const float*)d_in[2];   // [512,512]
    const float* b1  = (const float*)d_in[3];   // [512]
    const float* W2  = (const float*)d_in[4];   // [512,512]
    const float* b2  = (const float*)d_in[5];   // [512]
    const float* V   = (const float*)d_in[6];   // [512,1]
    // d_in[7] = bv: dead (softmax shift-invariance)

    float* out  = (float*)d_out;
    float* ctx  = out;                 // [64,512]
    float* attn = out + BATCH * DIM;   // [64,2048]

    char* ws = (char*)d_ws;
    float* pd            = (float*)ws;                                  // 128 KB
    unsigned short* w1t  = (unsigned short*)(ws + 131072);              // 512 KB
    float* scores        = (float*)(ws + 131072 + 524288);              // 512 KB
    float* cnum          = (float*)(ws + 131072 + 524288 + 524288);     // 128 KB
    float* zacc          = (float*)(ws + 131072 + 524288 + 524288 + 131072); // 256 B

    // zero the atomic accumulators (cnum + zacc are contiguous)
    hipMemsetAsync(cnum, 0, (size_t)BATCH * DIM * 4 + BATCH * 4, stream);

    prep_w1t_kernel<<<256, 256, 0, stream>>>(W1, w1t);
    proj_dec_v2<<<dim3(8, BATCH), 256, 0, stream>>>(dec, W2, b1, b2, pd);
    gemm_score_v7b<<<MROWS / BM7, 512, 0, stream>>>(enc, w1t, pd, V, scores,
                                                    cnum, zacc);
    finalize_kernel<<<dim3(4, BATCH), 256, 0, stream>>>(scores, cnum, zacc,
                                                        attn, ctx);
}